// Round 2
// baseline (222.445 us; speedup 1.0000x reference)
//
#include <hip/hip_runtime.h>
#include <cmath>

// CDF_origin_35407710388891: per-channel 1->3->3->3->1 pointwise MLP.
//   m_i = softplus(M_i); h = m_i @ h + b_i; h += tanh(f_i)*tanh(h) (i<3)
// C=320 channels, N=65536 samples/channel, fp32 in/out.
// Input dict order: inputs, M0, b0, f0, M1, b1, f1, M2, b2, f2, M3, b3, stop_gradient

#define CCH 320
#define NN 65536
#define BLK 256
#define BLOCKS_PER_CH 8   // 8*256 = 2048 threads/channel; 16384 float4 / 2048 = 8 iters

__device__ __forceinline__ float softplusf(float x) {
    // numerically-stable log1p(exp(x)); libm accuracy, only runs once/thread/weight
    return fmaxf(x, 0.0f) + log1pf(expf(-fabsf(x)));
}

__global__ __launch_bounds__(BLK) void cdf_mlp_kernel(
    const float* __restrict__ in,
    const float* __restrict__ M0, const float* __restrict__ b0, const float* __restrict__ f0,
    const float* __restrict__ M1, const float* __restrict__ b1, const float* __restrict__ f1,
    const float* __restrict__ M2, const float* __restrict__ b2, const float* __restrict__ f2,
    const float* __restrict__ M3, const float* __restrict__ b3,
    float* __restrict__ out)
{
    const int c = blockIdx.y;   // wave-uniform -> weight loads become scalar loads

    // ---- per-channel weights, transcendentals hoisted to once per thread ----
    float m0[3], B0[3], t0[3], B1[3], t1[3], B2[3], t2[3], m3[3];
    float m1[9], m2[9];
#pragma unroll
    for (int i = 0; i < 3; ++i) {
        m0[i] = softplusf(M0[c * 3 + i]);
        B0[i] = b0[c * 3 + i];
        t0[i] = tanhf(f0[c * 3 + i]);
        B1[i] = b1[c * 3 + i];
        t1[i] = tanhf(f1[c * 3 + i]);
        B2[i] = b2[c * 3 + i];
        t2[i] = tanhf(f2[c * 3 + i]);
        m3[i] = softplusf(M3[c * 3 + i]);
    }
#pragma unroll
    for (int i = 0; i < 9; ++i) {
        m1[i] = softplusf(M1[c * 9 + i]);
        m2[i] = softplusf(M2[c * 9 + i]);
    }
    const float B3 = b3[c];

    // wave-uniform gates: tanh(f)==0 => gating term vanishes, skip per-element tanh
    const bool g0 = (t0[0] != 0.f) || (t0[1] != 0.f) || (t0[2] != 0.f);
    const bool g1 = (t1[0] != 0.f) || (t1[1] != 0.f) || (t1[2] != 0.f);
    const bool g2 = (t2[0] != 0.f) || (t2[1] != 0.f) || (t2[2] != 0.f);

    const float4* __restrict__ inv  = reinterpret_cast<const float4*>(in + (size_t)c * NN);
    float4* __restrict__       outv = reinterpret_cast<float4*>(out + (size_t)c * NN);

    const int tid    = blockIdx.x * BLK + threadIdx.x;
    const int stride = BLOCKS_PER_CH * BLK;           // 2048 float4
    constexpr int ITERS = (NN / 4) / (BLOCKS_PER_CH * BLK);  // 8

#pragma unroll
    for (int it = 0; it < ITERS; ++it) {
        const int i = tid + it * stride;
        const float4 x = inv[i];
        float r[4] = {x.x, x.y, x.z, x.w};
#pragma unroll
        for (int k = 0; k < 4; ++k) {
            const float v = r[k];
            float h0[3], h1[3], h2[3];
#pragma unroll
            for (int j = 0; j < 3; ++j) h0[j] = fmaf(m0[j], v, B0[j]);
            if (g0) {
#pragma unroll
                for (int j = 0; j < 3; ++j) h0[j] = fmaf(t0[j], tanhf(h0[j]), h0[j]);
            }
#pragma unroll
            for (int j = 0; j < 3; ++j)
                h1[j] = fmaf(m1[j * 3 + 0], h0[0],
                        fmaf(m1[j * 3 + 1], h0[1],
                        fmaf(m1[j * 3 + 2], h0[2], B1[j])));
            if (g1) {
#pragma unroll
                for (int j = 0; j < 3; ++j) h1[j] = fmaf(t1[j], tanhf(h1[j]), h1[j]);
            }
#pragma unroll
            for (int j = 0; j < 3; ++j)
                h2[j] = fmaf(m2[j * 3 + 0], h1[0],
                        fmaf(m2[j * 3 + 1], h1[1],
                        fmaf(m2[j * 3 + 2], h1[2], B2[j])));
            if (g2) {
#pragma unroll
                for (int j = 0; j < 3; ++j) h2[j] = fmaf(t2[j], tanhf(h2[j]), h2[j]);
            }
            r[k] = fmaf(m3[0], h2[0], fmaf(m3[1], h2[1], fmaf(m3[2], h2[2], B3)));
        }
        outv[i] = make_float4(r[0], r[1], r[2], r[3]);
    }
}

extern "C" void kernel_launch(void* const* d_in, const int* in_sizes, int n_in,
                              void* d_out, int out_size, void* d_ws, size_t ws_size,
                              hipStream_t stream) {
    const float* in = (const float*)d_in[0];
    const float* M0 = (const float*)d_in[1];
    const float* b0 = (const float*)d_in[2];
    const float* f0 = (const float*)d_in[3];
    const float* M1 = (const float*)d_in[4];
    const float* b1 = (const float*)d_in[5];
    const float* f1 = (const float*)d_in[6];
    const float* M2 = (const float*)d_in[7];
    const float* b2 = (const float*)d_in[8];
    const float* f2 = (const float*)d_in[9];
    const float* M3 = (const float*)d_in[10];
    const float* b3 = (const float*)d_in[11];
    float* out = (float*)d_out;

    dim3 grid(BLOCKS_PER_CH, CCH);
    cdf_mlp_kernel<<<grid, BLK, 0, stream>>>(in, M0, b0, f0, M1, b1, f1,
                                             M2, b2, f2, M3, b3, out);
}

// Round 4
// 178.586 us; speedup vs baseline: 1.2456x; 1.2456x over previous
//
#include <hip/hip_runtime.h>
#include <cmath>

// CDF_origin_35407710388891: per-channel 1->3->3->3->1 pointwise MLP.
//   m_i = softplus(M_i); h = m_i @ h + b_i; h += tanh(f_i)*tanh(h) (i<3)
// C=320, N=65536, fp32. With tanh(f_i)==0 (true for the given data) the whole
// net is affine in v: out = a*v + b. Precompute (a,b) per channel once
// (kernel 1), then stream 1 FMA/element (kernel 2). Fallback path for
// nonzero gates kept for general correctness.
// Input order: inputs, M0, b0, f0, M1, b1, f1, M2, b2, f2, M3, b3, stop_gradient

#define CCH 320
#define NN 65536
#define BLK 256
#define BLOCKS_PER_CH 8            // 2048 threads/ch; 16384 float4 / 2048 = 8 iters
#define WS_STRIDE 64               // floats per channel in d_ws

typedef float vfloat4 __attribute__((ext_vector_type(4)));  // native vec for nt-store

// ws layout per channel (float index):
// [0]=a [1]=b [2]=gateflag(0/1)
// [4..6]=m0 [7..9]=B0 [10..12]=t0 [13..21]=m1 [22..24]=B1 [25..27]=t1
// [28..36]=m2 [37..39]=B2 [40..42]=t2 [43..45]=m3 [46]=B3

__device__ __forceinline__ float softplusf(float x) {
    return fmaxf(x, 0.0f) + log1pf(expf(-fabsf(x)));
}

__global__ __launch_bounds__(BLK) void cdf_precompute_kernel(
    const float* __restrict__ M0, const float* __restrict__ b0, const float* __restrict__ f0,
    const float* __restrict__ M1, const float* __restrict__ b1, const float* __restrict__ f1,
    const float* __restrict__ M2, const float* __restrict__ b2, const float* __restrict__ f2,
    const float* __restrict__ M3, const float* __restrict__ b3,
    float* __restrict__ ws)
{
    const int c = blockIdx.x * BLK + threadIdx.x;
    if (c >= CCH) return;
    float* w = ws + (size_t)c * WS_STRIDE;

    float m0[3], B0[3], t0[3], m1[9], B1[3], t1[3], m2[9], B2[3], t2[3], m3[3];
#pragma unroll
    for (int i = 0; i < 3; ++i) {
        m0[i] = softplusf(M0[c * 3 + i]);
        B0[i] = b0[c * 3 + i];
        t0[i] = tanhf(f0[c * 3 + i]);
        B1[i] = b1[c * 3 + i];
        t1[i] = tanhf(f1[c * 3 + i]);
        B2[i] = b2[c * 3 + i];
        t2[i] = tanhf(f2[c * 3 + i]);
        m3[i] = softplusf(M3[c * 3 + i]);
    }
#pragma unroll
    for (int i = 0; i < 9; ++i) {
        m1[i] = softplusf(M1[c * 9 + i]);
        m2[i] = softplusf(M2[c * 9 + i]);
    }
    const float B3 = b3[c];

    const bool gated = t0[0] != 0.f || t0[1] != 0.f || t0[2] != 0.f ||
                       t1[0] != 0.f || t1[1] != 0.f || t1[2] != 0.f ||
                       t2[0] != 0.f || t2[1] != 0.f || t2[2] != 0.f;

    // affine composition in fp64: out = a*v + b
    double w1[3], u1[3], w2[3], u2[3];
#pragma unroll
    for (int i = 0; i < 3; ++i) {
        w1[i] = (double)m1[i*3+0]*m0[0] + (double)m1[i*3+1]*m0[1] + (double)m1[i*3+2]*m0[2];
        u1[i] = (double)m1[i*3+0]*B0[0] + (double)m1[i*3+1]*B0[1] + (double)m1[i*3+2]*B0[2] + B1[i];
    }
#pragma unroll
    for (int i = 0; i < 3; ++i) {
        w2[i] = (double)m2[i*3+0]*w1[0] + (double)m2[i*3+1]*w1[1] + (double)m2[i*3+2]*w1[2];
        u2[i] = (double)m2[i*3+0]*u1[0] + (double)m2[i*3+1]*u1[1] + (double)m2[i*3+2]*u1[2] + B2[i];
    }
    const double a = (double)m3[0]*w2[0] + (double)m3[1]*w2[1] + (double)m3[2]*w2[2];
    const double b = (double)m3[0]*u2[0] + (double)m3[1]*u2[1] + (double)m3[2]*u2[2] + B3;

    w[0] = (float)a;
    w[1] = (float)b;
    w[2] = gated ? 1.0f : 0.0f;
#pragma unroll
    for (int i = 0; i < 3; ++i) {
        w[4 + i]  = m0[i];  w[7 + i]  = B0[i];  w[10 + i] = t0[i];
        w[22 + i] = B1[i];  w[25 + i] = t1[i];
        w[37 + i] = B2[i];  w[40 + i] = t2[i];  w[43 + i] = m3[i];
    }
#pragma unroll
    for (int i = 0; i < 9; ++i) { w[13 + i] = m1[i]; w[28 + i] = m2[i]; }
    w[46] = B3;
}

__global__ __launch_bounds__(BLK) void cdf_stream_kernel(
    const float* __restrict__ in, const float* __restrict__ ws,
    float* __restrict__ out)
{
    const int c = blockIdx.y;                       // wave-uniform
    const float* __restrict__ w = ws + (size_t)c * WS_STRIDE;

    const vfloat4* __restrict__ inv  = reinterpret_cast<const vfloat4*>(in + (size_t)c * NN);
    vfloat4* __restrict__       outv = reinterpret_cast<vfloat4*>(out + (size_t)c * NN);

    const int tid    = blockIdx.x * BLK + threadIdx.x;
    const int stride = BLOCKS_PER_CH * BLK;         // 2048 float4
    constexpr int ITERS = (NN / 4) / (BLOCKS_PER_CH * BLK);  // 8

    if (w[2] == 0.0f) {
        // ---- affine fast path: out = a*x + b (1 FMA / element) ----
        const float a = w[0], b = w[1];
#pragma unroll
        for (int it = 0; it < ITERS; ++it) {
            const int i = tid + it * stride;
            const vfloat4 x = inv[i];
            vfloat4 r;
            r.x = fmaf(a, x.x, b);
            r.y = fmaf(a, x.y, b);
            r.z = fmaf(a, x.z, b);
            r.w = fmaf(a, x.w, b);
            __builtin_nontemporal_store(r, &outv[i]);
        }
        return;
    }

    // ---- gated fallback (general data): full MLP with precomputed weights ----
    float m0[3], B0[3], t0[3], m1[9], B1[3], t1[3], m2[9], B2[3], t2[3], m3[3];
#pragma unroll
    for (int i = 0; i < 3; ++i) {
        m0[i] = w[4 + i];  B0[i] = w[7 + i];  t0[i] = w[10 + i];
        B1[i] = w[22 + i]; t1[i] = w[25 + i];
        B2[i] = w[37 + i]; t2[i] = w[40 + i]; m3[i] = w[43 + i];
    }
#pragma unroll
    for (int i = 0; i < 9; ++i) { m1[i] = w[13 + i]; m2[i] = w[28 + i]; }
    const float B3 = w[46];

#pragma unroll
    for (int it = 0; it < ITERS; ++it) {
        const int i = tid + it * stride;
        const vfloat4 x = inv[i];
        float r[4] = {x.x, x.y, x.z, x.w};
#pragma unroll
        for (int k = 0; k < 4; ++k) {
            const float v = r[k];
            float h0[3], h1[3], h2[3];
#pragma unroll
            for (int j = 0; j < 3; ++j) {
                h0[j] = fmaf(m0[j], v, B0[j]);
                h0[j] = fmaf(t0[j], tanhf(h0[j]), h0[j]);
            }
#pragma unroll
            for (int j = 0; j < 3; ++j) {
                h1[j] = fmaf(m1[j*3+0], h0[0],
                        fmaf(m1[j*3+1], h0[1],
                        fmaf(m1[j*3+2], h0[2], B1[j])));
                h1[j] = fmaf(t1[j], tanhf(h1[j]), h1[j]);
            }
#pragma unroll
            for (int j = 0; j < 3; ++j) {
                h2[j] = fmaf(m2[j*3+0], h1[0],
                        fmaf(m2[j*3+1], h1[1],
                        fmaf(m2[j*3+2], h1[2], B2[j])));
                h2[j] = fmaf(t2[j], tanhf(h2[j]), h2[j]);
            }
            r[k] = fmaf(m3[0], h2[0], fmaf(m3[1], h2[1], fmaf(m3[2], h2[2], B3)));
        }
        vfloat4 o; o.x = r[0]; o.y = r[1]; o.z = r[2]; o.w = r[3];
        outv[i] = o;
    }
}

extern "C" void kernel_launch(void* const* d_in, const int* in_sizes, int n_in,
                              void* d_out, int out_size, void* d_ws, size_t ws_size,
                              hipStream_t stream) {
    const float* in = (const float*)d_in[0];
    const float* M0 = (const float*)d_in[1];
    const float* b0 = (const float*)d_in[2];
    const float* f0 = (const float*)d_in[3];
    const float* M1 = (const float*)d_in[4];
    const float* b1 = (const float*)d_in[5];
    const float* f1 = (const float*)d_in[6];
    const float* M2 = (const float*)d_in[7];
    const float* b2 = (const float*)d_in[8];
    const float* f2 = (const float*)d_in[9];
    const float* M3 = (const float*)d_in[10];
    const float* b3 = (const float*)d_in[11];
    float* out = (float*)d_out;
    float* ws  = (float*)d_ws;     // needs 320*64*4 = 80 KB

    cdf_precompute_kernel<<<dim3((CCH + BLK - 1) / BLK), BLK, 0, stream>>>(
        M0, b0, f0, M1, b1, f1, M2, b2, f2, M3, b3, ws);

    dim3 grid(BLOCKS_PER_CH, CCH);
    cdf_stream_kernel<<<grid, BLK, 0, stream>>>(in, ws, out);
}

// Round 6
// 174.598 us; speedup vs baseline: 1.2740x; 1.0228x over previous
//
#include <hip/hip_runtime.h>
#include <cmath>

// CDF_origin_35407710388891: per-channel 1->3->3->3->1 pointwise MLP.
//   m_i = softplus(M_i); h = m_i @ h + b_i; h += tanh(f_i)*tanh(h) (i<3)
// C=320, N=65536, fp32. With tanh(f_i)==0 (true for the given data) the whole
// net is affine in v: out = a*v + b. Precompute (a,b) per channel once
// (kernel 1, fast transcendentals + fp64 composition), then stream
// 1 FMA/element (kernel 2, plain float4 stores — NT store was suspect #1
// for the 2x-roofline gap; fills prove plain stores hit 6.5 TB/s).
// Fallback path for nonzero gates kept for general correctness.
// Input order: inputs, M0, b0, f0, M1, b1, f1, M2, b2, f2, M3, b3, stop_gradient

#define CCH 320
#define NN 65536
#define BLK 256
#define BLOCKS_PER_CH 8            // 2048 threads/ch; 16384 float4 / 2048 = 8 iters
#define WS_STRIDE 64               // floats per channel in d_ws

typedef float vfloat4 __attribute__((ext_vector_type(4)));

// ws layout per channel (float index):
// [0]=a [1]=b [2]=gateflag(0/1)
// [4..6]=m0 [7..9]=B0 [10..12]=t0 [13..21]=m1 [22..24]=B1 [25..27]=t1
// [28..36]=m2 [37..39]=B2 [40..42]=t2 [43..45]=m3 [46]=B3

// fast softplus: max(x,0) + log(1+exp(-|x|)); 1+y in (1,2] so plain log is
// exact enough (log1p only matters for y tiny, where abs err < 1e-38)
__device__ __forceinline__ float softplus_fast(float x) {
    return fmaxf(x, 0.0f) + __logf(1.0f + __expf(-fabsf(x)));
}
// fast tanh: 1 - 2/(exp(2x)+1); exact 0 at x=0, saturates correctly
__device__ __forceinline__ float tanh_fast(float x) {
    return 1.0f - 2.0f / (__expf(2.0f * x) + 1.0f);
}

__global__ __launch_bounds__(BLK) void cdf_precompute_kernel(
    const float* __restrict__ M0, const float* __restrict__ b0, const float* __restrict__ f0,
    const float* __restrict__ M1, const float* __restrict__ b1, const float* __restrict__ f1,
    const float* __restrict__ M2, const float* __restrict__ b2, const float* __restrict__ f2,
    const float* __restrict__ M3, const float* __restrict__ b3,
    float* __restrict__ ws)
{
    const int c = blockIdx.x * BLK + threadIdx.x;
    if (c >= CCH) return;
    float* w = ws + (size_t)c * WS_STRIDE;

    float m0[3], B0[3], t0[3], m1[9], B1[3], t1[3], m2[9], B2[3], t2[3], m3[3];
#pragma unroll
    for (int i = 0; i < 3; ++i) {
        m0[i] = softplus_fast(M0[c * 3 + i]);
        B0[i] = b0[c * 3 + i];
        t0[i] = tanh_fast(f0[c * 3 + i]);
        B1[i] = b1[c * 3 + i];
        t1[i] = tanh_fast(f1[c * 3 + i]);
        B2[i] = b2[c * 3 + i];
        t2[i] = tanh_fast(f2[c * 3 + i]);
        m3[i] = softplus_fast(M3[c * 3 + i]);
    }
#pragma unroll
    for (int i = 0; i < 9; ++i) {
        m1[i] = softplus_fast(M1[c * 9 + i]);
        m2[i] = softplus_fast(M2[c * 9 + i]);
    }
    const float B3 = b3[c];

    const bool gated = t0[0] != 0.f || t0[1] != 0.f || t0[2] != 0.f ||
                       t1[0] != 0.f || t1[1] != 0.f || t1[2] != 0.f ||
                       t2[0] != 0.f || t2[1] != 0.f || t2[2] != 0.f;

    // affine composition in fp64 (cheap, ~40 ops): out = a*v + b
    double w1[3], u1[3], w2[3], u2[3];
#pragma unroll
    for (int i = 0; i < 3; ++i) {
        w1[i] = (double)m1[i*3+0]*m0[0] + (double)m1[i*3+1]*m0[1] + (double)m1[i*3+2]*m0[2];
        u1[i] = (double)m1[i*3+0]*B0[0] + (double)m1[i*3+1]*B0[1] + (double)m1[i*3+2]*B0[2] + B1[i];
    }
#pragma unroll
    for (int i = 0; i < 3; ++i) {
        w2[i] = (double)m2[i*3+0]*w1[0] + (double)m2[i*3+1]*w1[1] + (double)m2[i*3+2]*w1[2];
        u2[i] = (double)m2[i*3+0]*u1[0] + (double)m2[i*3+1]*u1[1] + (double)m2[i*3+2]*u1[2] + B2[i];
    }
    const double a = (double)m3[0]*w2[0] + (double)m3[1]*w2[1] + (double)m3[2]*w2[2];
    const double b = (double)m3[0]*u2[0] + (double)m3[1]*u2[1] + (double)m3[2]*u2[2] + B3;

    w[0] = (float)a;
    w[1] = (float)b;
    w[2] = gated ? 1.0f : 0.0f;
#pragma unroll
    for (int i = 0; i < 3; ++i) {
        w[4 + i]  = m0[i];  w[7 + i]  = B0[i];  w[10 + i] = t0[i];
        w[22 + i] = B1[i];  w[25 + i] = t1[i];
        w[37 + i] = B2[i];  w[40 + i] = t2[i];  w[43 + i] = m3[i];
    }
#pragma unroll
    for (int i = 0; i < 9; ++i) { w[13 + i] = m1[i]; w[28 + i] = m2[i]; }
    w[46] = B3;
}

__global__ __launch_bounds__(BLK) void cdf_stream_kernel(
    const float* __restrict__ in, const float* __restrict__ ws,
    float* __restrict__ out)
{
    const int c = blockIdx.y;                       // wave-uniform
    const float* __restrict__ w = ws + (size_t)c * WS_STRIDE;

    const vfloat4* __restrict__ inv  = reinterpret_cast<const vfloat4*>(in + (size_t)c * NN);
    vfloat4* __restrict__       outv = reinterpret_cast<vfloat4*>(out + (size_t)c * NN);

    const int tid    = blockIdx.x * BLK + threadIdx.x;
    const int stride = BLOCKS_PER_CH * BLK;         // 2048 float4
    constexpr int ITERS = (NN / 4) / (BLOCKS_PER_CH * BLK);  // 8

    if (__builtin_expect(w[2] == 0.0f, 1)) {
        // ---- affine fast path: out = a*x + b (1 FMA / element), plain stores ----
        const float a = w[0], b = w[1];
#pragma unroll
        for (int it = 0; it < ITERS; ++it) {
            const int i = tid + it * stride;
            const vfloat4 x = inv[i];
            vfloat4 r;
            r.x = fmaf(a, x.x, b);
            r.y = fmaf(a, x.y, b);
            r.z = fmaf(a, x.z, b);
            r.w = fmaf(a, x.w, b);
            outv[i] = r;
        }
        return;
    }

    // ---- gated fallback (general data): full MLP with precomputed weights ----
    float m0[3], B0[3], t0[3], m1[9], B1[3], t1[3], m2[9], B2[3], t2[3], m3[3];
#pragma unroll
    for (int i = 0; i < 3; ++i) {
        m0[i] = w[4 + i];  B0[i] = w[7 + i];  t0[i] = w[10 + i];
        B1[i] = w[22 + i]; t1[i] = w[25 + i];
        B2[i] = w[37 + i]; t2[i] = w[40 + i]; m3[i] = w[43 + i];
    }
#pragma unroll
    for (int i = 0; i < 9; ++i) { m1[i] = w[13 + i]; m2[i] = w[28 + i]; }
    const float B3 = w[46];

#pragma unroll
    for (int it = 0; it < ITERS; ++it) {
        const int i = tid + it * stride;
        const vfloat4 x = inv[i];
        float r[4] = {x.x, x.y, x.z, x.w};
#pragma unroll
        for (int k = 0; k < 4; ++k) {
            const float v = r[k];
            float h0[3], h1[3], h2[3];
#pragma unroll
            for (int j = 0; j < 3; ++j) {
                h0[j] = fmaf(m0[j], v, B0[j]);
                h0[j] = fmaf(t0[j], tanh_fast(h0[j]), h0[j]);
            }
#pragma unroll
            for (int j = 0; j < 3; ++j) {
                h1[j] = fmaf(m1[j*3+0], h0[0],
                        fmaf(m1[j*3+1], h0[1],
                        fmaf(m1[j*3+2], h0[2], B1[j])));
                h1[j] = fmaf(t1[j], tanh_fast(h1[j]), h1[j]);
            }
#pragma unroll
            for (int j = 0; j < 3; ++j) {
                h2[j] = fmaf(m2[j*3+0], h1[0],
                        fmaf(m2[j*3+1], h1[1],
                        fmaf(m2[j*3+2], h1[2], B2[j])));
                h2[j] = fmaf(t2[j], tanh_fast(h2[j]), h2[j]);
            }
            r[k] = fmaf(m3[0], h2[0], fmaf(m3[1], h2[1], fmaf(m3[2], h2[2], B3)));
        }
        vfloat4 o; o.x = r[0]; o.y = r[1]; o.z = r[2]; o.w = r[3];
        outv[i] = o;
    }
}

extern "C" void kernel_launch(void* const* d_in, const int* in_sizes, int n_in,
                              void* d_out, int out_size, void* d_ws, size_t ws_size,
                              hipStream_t stream) {
    const float* in = (const float*)d_in[0];
    const float* M0 = (const float*)d_in[1];
    const float* b0 = (const float*)d_in[2];
    const float* f0 = (const float*)d_in[3];
    const float* M1 = (const float*)d_in[4];
    const float* b1 = (const float*)d_in[5];
    const float* f1 = (const float*)d_in[6];
    const float* M2 = (const float*)d_in[7];
    const float* b2 = (const float*)d_in[8];
    const float* f2 = (const float*)d_in[9];
    const float* M3 = (const float*)d_in[10];
    const float* b3 = (const float*)d_in[11];
    float* out = (float*)d_out;
    float* ws  = (float*)d_ws;     // needs 320*64*4 = 80 KB

    cdf_precompute_kernel<<<dim3((CCH + BLK - 1) / BLK), BLK, 0, stream>>>(
        M0, b0, f0, M1, b1, f1, M2, b2, f2, M3, b3, ws);

    dim3 grid(BLOCKS_PER_CH, CCH);
    cdf_stream_kernel<<<grid, BLK, 0, stream>>>(in, ws, out);
}

// Round 7
// 170.369 us; speedup vs baseline: 1.3057x; 1.0248x over previous
//
#include <hip/hip_runtime.h>
#include <cmath>

// CDF_origin_35407710388891: per-channel 1->3->3->3->1 pointwise MLP.
//   m_i = softplus(M_i); h = m_i @ h + b_i; h += tanh(f_i)*tanh(h) (i<3)
// C=320, N=65536, fp32. With tanh(f_i)==0 (true for the given data) the whole
// net is affine in v: out = a*v + b.
// SINGLE fused kernel: each block derives its channel's (a,b) from the raw
// weights (block-uniform loads -> s_load; ~400 VALU cycles/wave, noise vs the
// ~62K-cycle/CU memory budget), then streams 1 FMA/element. Gate test needs
// no tanh (tanh(x)!=0 iff x!=0). Full MLP fallback kept for nonzero gates.
// Input order: inputs, M0, b0, f0, M1, b1, f1, M2, b2, f2, M3, b3, stop_gradient

#define CCH 320
#define NN 65536
#define BLK 256
#define BLOCKS_PER_CH 8            // 2048 threads/ch; 16384 float4 / 2048 = 8 iters

typedef float vfloat4 __attribute__((ext_vector_type(4)));

// fast softplus: max(x,0) + log(1+exp(-|x|)); arg of log in (1,2] so plain
// __logf is fine (same formula as round 6 -> same absmax, passes)
__device__ __forceinline__ float softplus_fast(float x) {
    return fmaxf(x, 0.0f) + __logf(1.0f + __expf(-fabsf(x)));
}
// fast tanh: 1 - 2/(exp(2x)+1); exact 0 at x=0, saturates correctly
__device__ __forceinline__ float tanh_fast(float x) {
    return 1.0f - 2.0f / (__expf(2.0f * x) + 1.0f);
}

__global__ __launch_bounds__(BLK) void cdf_fused_kernel(
    const float* __restrict__ in,
    const float* __restrict__ M0, const float* __restrict__ b0, const float* __restrict__ f0,
    const float* __restrict__ M1, const float* __restrict__ b1, const float* __restrict__ f1,
    const float* __restrict__ M2, const float* __restrict__ b2, const float* __restrict__ f2,
    const float* __restrict__ M3, const float* __restrict__ b3,
    float* __restrict__ out)
{
    const int c   = blockIdx.x >> 3;          // channel; block-uniform
    const int sub = blockIdx.x & 7;           // sub-tile within channel

    const vfloat4* __restrict__ inv  = reinterpret_cast<const vfloat4*>(in  + (size_t)c * NN);
    vfloat4* __restrict__       outv = reinterpret_cast<vfloat4*>(out + (size_t)c * NN);

    const int tid    = sub * BLK + threadIdx.x;        // 0..2047 within channel
    const int stride = BLOCKS_PER_CH * BLK;            // 2048 float4
    constexpr int ITERS = (NN / 4) / (BLOCKS_PER_CH * BLK);  // 8

    // ---- per-channel weights (uniform addresses -> scalar loads) ----
    // gate: tanh(x) != 0  <=>  x != 0, so no tanh needed for the test
    const bool gated = f0[c*3+0] != 0.f || f0[c*3+1] != 0.f || f0[c*3+2] != 0.f ||
                       f1[c*3+0] != 0.f || f1[c*3+1] != 0.f || f1[c*3+2] != 0.f ||
                       f2[c*3+0] != 0.f || f2[c*3+1] != 0.f || f2[c*3+2] != 0.f;

    float m0[3], B0[3], m1[9], B1[3], m2[9], B2[3], m3[3];
#pragma unroll
    for (int i = 0; i < 3; ++i) {
        m0[i] = softplus_fast(M0[c*3+i]);
        B0[i] = b0[c*3+i];
        B1[i] = b1[c*3+i];
        B2[i] = b2[c*3+i];
        m3[i] = softplus_fast(M3[c*3+i]);
    }
#pragma unroll
    for (int i = 0; i < 9; ++i) {
        m1[i] = softplus_fast(M1[c*9+i]);
        m2[i] = softplus_fast(M2[c*9+i]);
    }
    const float B3 = b3[c];

    if (__builtin_expect(!gated, 1)) {
        // ---- affine compose in fp64 (identical arithmetic to round 6) ----
        double w1[3], u1[3], w2[3], u2[3];
#pragma unroll
        for (int i = 0; i < 3; ++i) {
            w1[i] = (double)m1[i*3+0]*m0[0] + (double)m1[i*3+1]*m0[1] + (double)m1[i*3+2]*m0[2];
            u1[i] = (double)m1[i*3+0]*B0[0] + (double)m1[i*3+1]*B0[1] + (double)m1[i*3+2]*B0[2] + B1[i];
        }
#pragma unroll
        for (int i = 0; i < 3; ++i) {
            w2[i] = (double)m2[i*3+0]*w1[0] + (double)m2[i*3+1]*w1[1] + (double)m2[i*3+2]*w1[2];
            u2[i] = (double)m2[i*3+0]*u1[0] + (double)m2[i*3+1]*u1[1] + (double)m2[i*3+2]*u1[2] + B2[i];
        }
        const float a = (float)((double)m3[0]*w2[0] + (double)m3[1]*w2[1] + (double)m3[2]*w2[2]);
        const float b = (float)((double)m3[0]*u2[0] + (double)m3[1]*u2[1] + (double)m3[2]*u2[2] + B3);

        // ---- stream: out = a*x + b, 1 FMA / element ----
#pragma unroll
        for (int it = 0; it < ITERS; ++it) {
            const int i = tid + it * stride;
            const vfloat4 x = inv[i];
            vfloat4 r;
            r.x = fmaf(a, x.x, b);
            r.y = fmaf(a, x.y, b);
            r.z = fmaf(a, x.z, b);
            r.w = fmaf(a, x.w, b);
            outv[i] = r;
        }
        return;
    }

    // ---- gated fallback (general data): full MLP per element ----
    float t0[3], t1[3], t2[3];
#pragma unroll
    for (int i = 0; i < 3; ++i) {
        t0[i] = tanh_fast(f0[c*3+i]);
        t1[i] = tanh_fast(f1[c*3+i]);
        t2[i] = tanh_fast(f2[c*3+i]);
    }

#pragma unroll
    for (int it = 0; it < ITERS; ++it) {
        const int i = tid + it * stride;
        const vfloat4 x = inv[i];
        float r[4] = {x.x, x.y, x.z, x.w};
#pragma unroll
        for (int k = 0; k < 4; ++k) {
            const float v = r[k];
            float h0[3], h1[3], h2[3];
#pragma unroll
            for (int j = 0; j < 3; ++j) {
                h0[j] = fmaf(m0[j], v, B0[j]);
                h0[j] = fmaf(t0[j], tanh_fast(h0[j]), h0[j]);
            }
#pragma unroll
            for (int j = 0; j < 3; ++j) {
                h1[j] = fmaf(m1[j*3+0], h0[0],
                        fmaf(m1[j*3+1], h0[1],
                        fmaf(m1[j*3+2], h0[2], B1[j])));
                h1[j] = fmaf(t1[j], tanh_fast(h1[j]), h1[j]);
            }
#pragma unroll
            for (int j = 0; j < 3; ++j) {
                h2[j] = fmaf(m2[j*3+0], h1[0],
                        fmaf(m2[j*3+1], h1[1],
                        fmaf(m2[j*3+2], h1[2], B2[j])));
                h2[j] = fmaf(t2[j], tanh_fast(h2[j]), h2[j]);
            }
            r[k] = fmaf(m3[0], h2[0], fmaf(m3[1], h2[1], fmaf(m3[2], h2[2], B3)));
        }
        vfloat4 o; o.x = r[0]; o.y = r[1]; o.z = r[2]; o.w = r[3];
        outv[i] = o;
    }
}

extern "C" void kernel_launch(void* const* d_in, const int* in_sizes, int n_in,
                              void* d_out, int out_size, void* d_ws, size_t ws_size,
                              hipStream_t stream) {
    const float* in = (const float*)d_in[0];
    const float* M0 = (const float*)d_in[1];
    const float* b0 = (const float*)d_in[2];
    const float* f0 = (const float*)d_in[3];
    const float* M1 = (const float*)d_in[4];
    const float* b1 = (const float*)d_in[5];
    const float* f1 = (const float*)d_in[6];
    const float* M2 = (const float*)d_in[7];
    const float* b2 = (const float*)d_in[8];
    const float* f2 = (const float*)d_in[9];
    const float* M3 = (const float*)d_in[10];
    const float* b3 = (const float*)d_in[11];
    float* out = (float*)d_out;

    cdf_fused_kernel<<<dim3(CCH * BLOCKS_PER_CH), BLK, 0, stream>>>(
        in, M0, b0, f0, M1, b1, f1, M2, b2, f2, M3, b3, out);
}

// Round 9
// 170.110 us; speedup vs baseline: 1.3077x; 1.0015x over previous
//
#include <hip/hip_runtime.h>
#include <cmath>

// CDF_origin_35407710388891: per-channel 1->3->3->3->1 pointwise MLP.
//   m_i = softplus(M_i); h = m_i @ h + b_i; h += tanh(f_i)*tanh(h) (i<3)
// C=320, N=65536, fp32. tanh(f_i)==0 for the given data => net is affine:
// out = a*v + b, with (a,b) composed per channel from softplus'd weights.
// Single fused kernel; weights via block-uniform (scalar) loads.
// R7 change: EXPLICIT LOAD BATCHING — all 8 float4 loads issued before any
// compute/store (VGPR=52 suggested ~1 load in flight/wave -> latency-bound
// at 3.4 TB/s; 8 in flight should reach ~6 TB/s).
// Input order: inputs, M0, b0, f0, M1, b1, f1, M2, b2, f2, M3, b3, stop_gradient

#define CCH 320
#define NN 65536
#define BLK 256
#define BLOCKS_PER_CH 8            // 2048 threads/ch; 16384 float4 / 2048 = 8 iters

typedef float vfloat4 __attribute__((ext_vector_type(4)));

__device__ __forceinline__ float softplus_fast(float x) {
    return fmaxf(x, 0.0f) + __logf(1.0f + __expf(-fabsf(x)));
}
__device__ __forceinline__ float tanh_fast(float x) {
    return 1.0f - 2.0f / (__expf(2.0f * x) + 1.0f);
}

__global__ __launch_bounds__(BLK) void cdf_fused_kernel(
    const float* __restrict__ in,
    const float* __restrict__ M0, const float* __restrict__ b0, const float* __restrict__ f0,
    const float* __restrict__ M1, const float* __restrict__ b1, const float* __restrict__ f1,
    const float* __restrict__ M2, const float* __restrict__ b2, const float* __restrict__ f2,
    const float* __restrict__ M3, const float* __restrict__ b3,
    float* __restrict__ out)
{
    const int c   = blockIdx.x >> 3;          // channel; block-uniform
    const int sub = blockIdx.x & 7;           // sub-tile within channel

    const vfloat4* __restrict__ inv  = reinterpret_cast<const vfloat4*>(in  + (size_t)c * NN);
    vfloat4* __restrict__       outv = reinterpret_cast<vfloat4*>(out + (size_t)c * NN);

    const int tid    = sub * BLK + threadIdx.x;        // 0..2047 within channel
    const int stride = BLOCKS_PER_CH * BLK;            // 2048 float4
    constexpr int ITERS = (NN / 4) / (BLOCKS_PER_CH * BLK);  // 8

    // ---- issue ALL input loads first: 8 independent dwordx4 in flight ----
    vfloat4 x[ITERS];
#pragma unroll
    for (int it = 0; it < ITERS; ++it)
        x[it] = inv[tid + it * stride];

    // ---- per-channel weights (uniform addresses -> scalar loads);
    //      latency overlaps with the vector loads above ----
    const bool gated = f0[c*3+0] != 0.f || f0[c*3+1] != 0.f || f0[c*3+2] != 0.f ||
                       f1[c*3+0] != 0.f || f1[c*3+1] != 0.f || f1[c*3+2] != 0.f ||
                       f2[c*3+0] != 0.f || f2[c*3+1] != 0.f || f2[c*3+2] != 0.f;

    float m0[3], B0[3], m1[9], B1[3], m2[9], B2[3], m3[3];
#pragma unroll
    for (int i = 0; i < 3; ++i) {
        m0[i] = softplus_fast(M0[c*3+i]);
        B0[i] = b0[c*3+i];
        B1[i] = b1[c*3+i];
        B2[i] = b2[c*3+i];
        m3[i] = softplus_fast(M3[c*3+i]);
    }
#pragma unroll
    for (int i = 0; i < 9; ++i) {
        m1[i] = softplus_fast(M1[c*9+i]);
        m2[i] = softplus_fast(M2[c*9+i]);
    }
    const float B3 = b3[c];

    if (__builtin_expect(!gated, 1)) {
        // ---- affine compose in fp64 (identical arithmetic to round 6/7) ----
        double w1[3], u1[3], w2[3], u2[3];
#pragma unroll
        for (int i = 0; i < 3; ++i) {
            w1[i] = (double)m1[i*3+0]*m0[0] + (double)m1[i*3+1]*m0[1] + (double)m1[i*3+2]*m0[2];
            u1[i] = (double)m1[i*3+0]*B0[0] + (double)m1[i*3+1]*B0[1] + (double)m1[i*3+2]*B0[2] + B1[i];
        }
#pragma unroll
        for (int i = 0; i < 3; ++i) {
            w2[i] = (double)m2[i*3+0]*w1[0] + (double)m2[i*3+1]*w1[1] + (double)m2[i*3+2]*w1[2];
            u2[i] = (double)m2[i*3+0]*u1[0] + (double)m2[i*3+1]*u1[1] + (double)m2[i*3+2]*u1[2] + B2[i];
        }
        const float a = (float)((double)m3[0]*w2[0] + (double)m3[1]*w2[1] + (double)m3[2]*w2[2]);
        const float b = (float)((double)m3[0]*u2[0] + (double)m3[1]*u2[1] + (double)m3[2]*u2[2] + B3);

        // ---- drain loads in order: fma + store as each arrives ----
#pragma unroll
        for (int it = 0; it < ITERS; ++it) {
            vfloat4 r;
            r.x = fmaf(a, x[it].x, b);
            r.y = fmaf(a, x[it].y, b);
            r.z = fmaf(a, x[it].z, b);
            r.w = fmaf(a, x[it].w, b);
            outv[tid + it * stride] = r;
        }
        return;
    }

    // ---- gated fallback (general data): full MLP per element ----
    float t0[3], t1[3], t2[3];
#pragma unroll
    for (int i = 0; i < 3; ++i) {
        t0[i] = tanh_fast(f0[c*3+i]);
        t1[i] = tanh_fast(f1[c*3+i]);
        t2[i] = tanh_fast(f2[c*3+i]);
    }

#pragma unroll
    for (int it = 0; it < ITERS; ++it) {
        float r[4] = {x[it].x, x[it].y, x[it].z, x[it].w};
#pragma unroll
        for (int k = 0; k < 4; ++k) {
            const float v = r[k];
            float h0[3], h1[3], h2[3];
#pragma unroll
            for (int j = 0; j < 3; ++j) {
                h0[j] = fmaf(m0[j], v, B0[j]);
                h0[j] = fmaf(t0[j], tanh_fast(h0[j]), h0[j]);
            }
#pragma unroll
            for (int j = 0; j < 3; ++j) {
                h1[j] = fmaf(m1[j*3+0], h0[0],
                        fmaf(m1[j*3+1], h0[1],
                        fmaf(m1[j*3+2], h0[2], B1[j])));
                h1[j] = fmaf(t1[j], tanh_fast(h1[j]), h1[j]);
            }
#pragma unroll
            for (int j = 0; j < 3; ++j) {
                h2[j] = fmaf(m2[j*3+0], h1[0],
                        fmaf(m2[j*3+1], h1[1],
                        fmaf(m2[j*3+2], h1[2], B2[j])));
                h2[j] = fmaf(t2[j], tanh_fast(h2[j]), h2[j]);
            }
            r[k] = fmaf(m3[0], h2[0], fmaf(m3[1], h2[1], fmaf(m3[2], h2[2], B3)));
        }
        vfloat4 o; o.x = r[0]; o.y = r[1]; o.z = r[2]; o.w = r[3];
        outv[tid + it * stride] = o;
    }
}

extern "C" void kernel_launch(void* const* d_in, const int* in_sizes, int n_in,
                              void* d_out, int out_size, void* d_ws, size_t ws_size,
                              hipStream_t stream) {
    const float* in = (const float*)d_in[0];
    const float* M0 = (const float*)d_in[1];
    const float* b0 = (const float*)d_in[2];
    const float* f0 = (const float*)d_in[3];
    const float* M1 = (const float*)d_in[4];
    const float* b1 = (const float*)d_in[5];
    const float* f1 = (const float*)d_in[6];
    const float* M2 = (const float*)d_in[7];
    const float* b2 = (const float*)d_in[8];
    const float* f2 = (const float*)d_in[9];
    const float* M3 = (const float*)d_in[10];
    const float* b3 = (const float*)d_in[11];
    float* out = (float*)d_out;

    cdf_fused_kernel<<<dim3(CCH * BLOCKS_PER_CH), BLK, 0, stream>>>(
        in, M0, b0, f0, M1, b1, f1, M2, b2, f2, M3, b3, out);
}